// Round 11
// baseline (8785.730 us; speedup 1.0000x reference)
//
#include <hip/hip_runtime.h>
#include <math.h>

// ---------------------------------------------------------------------------
// Decoder_21371757265153 — v11: round decoder (v10 skeleton) with
//  (1) ROUNDS 1024 -> 640 + guaranteed-correct k_finish fallback
//      (expected no-op; covers adversarial inputs with >640 events),
//  (2) transposed weight slices SLT[sl][row][k]: per-row contiguous float4
//      streaming in both matvec halves (4x fewer VMEM instructions),
//  (3) unchanged: 16 seq x 16 row-slices, wave0-scan || W_hh*h half-matvec,
//      parity double-buffered state, kernel-boundary-only sync.
// Measured context: v8 7.39ms, v9 grid.sync 45.7ms (abandoned), v10 6.90ms;
// E_max inferred ~445 from v8->v10 delta arithmetic.
// ---------------------------------------------------------------------------

namespace {
constexpr int NB = 16;
constexpr int NT = 1024;
constexpr int NE = 768;
constexpr int NH = 384;
constexpr int NL = 33;
constexpr int ROUNDS = 640;    // even (k_finish reads slot 0)
constexpr int NSLICE = 16;
constexpr int JS = 24;
constexpr int RS = 96;

constexpr size_t OFF_SL   = 0;                         // SLT[sl][rho][k]
constexpr size_t N_SL     = (size_t)NSLICE * RS * NE;  // 1179648
constexpr size_t OFF_PEW  = OFF_SL + N_SL;
constexpr size_t N_PEW    = 32 * NH;
constexpr size_t OFF_ENCW = OFF_PEW + N_PEW;
constexpr size_t N_ENCW   = (size_t)NB * NT * NL;
constexpr size_t OFF_BS   = OFF_ENCW + N_ENCW;
constexpr size_t OFF_PC   = OFF_BS + 2048;
constexpr size_t N_PC     = (size_t)NB * 1025 * NH;
constexpr size_t OFF_STATE = OFF_PC + N_PC;
constexpr size_t ST_STRIDE = 4096;
constexpr int SX_HWBP = 64;    // 2 slots x [16][36]
constexpr int SX_H    = 1280;  // 2 slots x 512
constexpr int SX_C    = 2432;  // 384
constexpr int IX_T = 0, IX_WLEN = 1, IX_NW = 2, IX_NPOS = 3, IX_PLAST = 4,
              IX_LPEP = 5, IX_LPEE = 6, IX_DONE = 7;
}

__device__ __forceinline__ float sigmf(float x) { return 1.0f / (1.0f + expf(-x)); }

// ---- SLT[sl][rho][k] + posEmbW --------------------------------------------
// rho = gate*24+jj  ->  global row = gate*384 + sl*24 + jj ; k over [0,768)
__global__ void k_prep(const float* __restrict__ W_ih, const float* __restrict__ W_hh,
                       const float* __restrict__ W_cmb, const float* __restrict__ posEmb,
                       float* __restrict__ ws) {
    float* SL = ws + OFF_SL;
    float* pw = ws + OFF_PEW;
    const int n1 = (int)N_SL, n2 = (int)N_PEW;
    for (int i = blockIdx.x * blockDim.x + threadIdx.x; i < n1 + n2;
         i += gridDim.x * blockDim.x) {
        if (i < n1) {
            int sl = i / (RS * NE), rem = i % (RS * NE);
            int rho = rem / NE, k = rem % NE;
            int gate = rho / JS, jj = rho % JS;
            int grow = gate * NH + sl * JS + jj;
            SL[i] = (k < NH) ? W_ih[(size_t)grow * NH + k]
                             : W_hh[(size_t)grow * NH + (k - NH)];
        } else {
            int j3 = i - n1;
            int p = j3 / NH, j = j3 % NH;
            const float* pe = posEmb + p * 128;
            const float* wr = W_cmb + (size_t)j * 896;
            float a = 0.f;
            #pragma unroll 4
            for (int k = 0; k < 128; ++k) a += pe[k] * wr[k];
            pw[j3] = a;
        }
    }
}

// ---- encW[bt][l] = enc[bt,:] @ W_lin[l, 384:] -----------------------------
__global__ void k_encw(const float* __restrict__ enc, const float* __restrict__ W_lin,
                       float* __restrict__ ws) {
    float* encW = ws + OFF_ENCW;
    int gid = blockIdx.x * 256 + threadIdx.x;
    if (gid >= NB * NT * NL) return;
    int bt = gid / NL, l = gid % NL;
    const float4* e4 = (const float4*)(enc + (size_t)bt * NE);
    const float4* w4 = (const float4*)(W_lin + (size_t)l * 1152 + NH);
    float a0 = 0, a1 = 0, a2 = 0, a3 = 0;
    for (int k = 0; k < NE / 4; ++k) {
        float4 e = e4[k], w = w4[k];
        a0 += e.x * w.x; a1 += e.y * w.y; a2 += e.z * w.z; a3 += e.w * w.w;
    }
    encW[gid] = (a0 + a1) + (a2 + a3);
}

// ---- pc[b][t][j] = enc[b,t,:] @ W_cmb[j,128:]  (pre-prefix) ---------------
__global__ void k_encCmb(const float* __restrict__ enc, const float* __restrict__ W_cmb,
                         float* __restrict__ ws) {
    __shared__ float tile[16][NE];
    float* pc = ws + OFF_PC;
    int blk = blockIdx.x;
    int b = blk >> 6;
    int t0 = (blk & 63) * 16;
    for (int i = threadIdx.x; i < 16 * NE; i += 384) {
        int row = i / NE, k = i % NE;
        tile[row][k] = enc[((size_t)(b * NT + t0 + row)) * NE + k];
    }
    __syncthreads();
    int j = threadIdx.x;
    const float4* w4 = (const float4*)(W_cmb + (size_t)j * 896 + 128);
    float acc[16];
    #pragma unroll
    for (int r = 0; r < 16; ++r) acc[r] = 0.f;
    for (int q = 0; q < NE / 4; ++q) {
        float4 w = w4[q];
        #pragma unroll
        for (int r = 0; r < 16; ++r) {
            acc[r] += w.x * tile[r][q * 4] + w.y * tile[r][q * 4 + 1]
                    + w.z * tile[r][q * 4 + 2] + w.w * tile[r][q * 4 + 3];
        }
    }
    #pragma unroll
    for (int r = 0; r < 16; ++r)
        pc[((size_t)b * 1025 + t0 + r) * NH + j] = acc[r];
}

// ---- in-place exclusive prefix over t per (b,j) ---------------------------
__global__ void k_prefix(float* __restrict__ ws) {
    float* pc = ws + OFF_PC;
    int id = blockIdx.x * 256 + threadIdx.x;
    if (id >= NB * NH) return;
    int b = id / NH, j = id % NH;
    float* p = pc + ((size_t)b * 1025) * NH + j;
    float s = 0.f;
    for (int t = 0; t < NT; ++t) {
        float x = p[(size_t)t * NH];
        p[(size_t)t * NH] = s;
        s += x;
    }
    p[(size_t)NT * NH] = s;
}

// ---- init: slot-0 state, bsum ---------------------------------------------
__global__ void k_init(const float* __restrict__ b_ih, const float* __restrict__ b_hh,
                       const float* __restrict__ W_lin, const float* __restrict__ b_lin,
                       float* __restrict__ ws) {
    __shared__ float shh[NH], shc[NH], shw[NL];
    int tid = threadIdx.x;
    if (tid < NH) {
        float gi = b_ih[tid] + b_hh[tid];
        float gg = b_ih[2 * NH + tid] + b_hh[2 * NH + tid];
        float go = b_ih[3 * NH + tid] + b_hh[3 * NH + tid];
        float c = sigmf(gi) * tanhf(gg);
        float h = sigmf(go) * tanhf(c);
        shh[tid] = h; shc[tid] = c;
    }
    __syncthreads();
    if (tid < NL) {
        float a = b_lin[tid];
        for (int k = 0; k < NH; ++k) a += W_lin[(size_t)tid * 1152 + k] * shh[k];
        shw[tid] = a;
    }
    for (int i = tid; i < 4 * NH; i += 1024) ws[OFF_BS + i] = b_ih[i] + b_hh[i];
    __syncthreads();
    for (int s = 0; s < NB; ++s) {
        float* stf = ws + OFF_STATE + (size_t)s * ST_STRIDE;
        int* ii = (int*)stf;
        if (tid < 16) ii[tid] = (tid == IX_LPEP || tid == IX_LPEE) ? -1 : 0;
        if (tid >= 32 && tid < 32 + 576) {
            int i2 = tid - 32, r = i2 / 36, l = i2 % 36;
            stf[SX_HWBP + i2] = (r == 0 && l < NL) ? (shw[l] - b_lin[l]) : 0.f;
        }
        if (tid < NH) { stf[SX_H + tid] = shh[tid]; stf[SX_C + tid] = shc[tid]; }
    }
}

// ---- zero output ----------------------------------------------------------
__global__ void k_fill(float* __restrict__ out) {
    int i = blockIdx.x * 256 + threadIdx.x;
    if (i < NB * NT * NL) out[i] = 0.f;
}

// ---- k_round: scan (wave 0) || W_hh*h half-matvec; float4 row streams -----
__global__ __launch_bounds__(384) void k_round(
    const int* __restrict__ char_sizes,
    const int* __restrict__ label_is_sep, const int* __restrict__ label_pos_id,
    const float* __restrict__ W_lin, const float* __restrict__ b_lin,
    const float* __restrict__ b_cmb, float* __restrict__ ws,
    float* __restrict__ out, const int slot) {

    const int bid = blockIdx.x;
    const int s = bid >> 4;
    const int rh = bid & 15;
    const int tid = threadIdx.x;
    const int lane = tid & 63;
    const int wave = tid >> 6;

    float* stf = ws + OFF_STATE + (size_t)s * ST_STRIDE;
    int* ir = (int*)stf + slot * 16;
    int* iw = (int*)stf + (slot ^ 1) * 16;
    if (ir[IX_DONE]) return;

    const float* hWbp_r = stf + SX_HWBP + slot * 576;
    float*       hWbp_w = stf + SX_HWBP + (slot ^ 1) * 576;
    const float* h_r    = stf + SX_H + slot * 512;
    float*       h_w    = stf + SX_H + (slot ^ 1) * 512;
    float*       cst    = stf + SX_C;

    const float* SLw  = ws + OFF_SL + (size_t)rh * (RS * NE);
    const float* pew  = ws + OFF_PEW;
    const float* encW = ws + OFF_ENCW;
    const float* bsum = ws + OFF_BS;
    const float* pcb  = ws + OFF_PC + (size_t)s * 1025 * NH;

    __shared__ __align__(16) float sh_h[NH];
    __shared__ __align__(16) float sh_x[NH];
    __shared__ float sh_hWb[40], sh_part[384], sh_ph[288];
    __shared__ float sh_g[RS], sh_h2[JS];
    __shared__ int sh_issep[NL], sh_posid[NL], sh_scan[8];

    // prologue: h into LDS, c into registers
    sh_h[tid] = h_r[tid];
    float creg = (tid < JS) ? cst[rh * JS + tid] : 0.f;
    __syncthreads();

    if (wave == 0) {
        // ---- wave 0: tables + hWb + scan ----
        if (lane < NL) {
            sh_issep[lane] = label_is_sep[lane];
            sh_posid[lane] = label_pos_id[lane];
            float a = b_lin[lane];
            #pragma unroll
            for (int i = 0; i < 16; ++i) a += hWbp_r[i * 36 + lane];
            sh_hWb[lane] = a;
        }
        asm volatile("" ::: "memory");

        int t = ir[IX_T], wlen = ir[IX_WLEN], nw = ir[IX_NW], npos = ir[IX_NPOS],
            plast = ir[IX_PLAST], lpe_pend = ir[IX_LPEP], lpe_eff = ir[IX_LPEE];
        int size = char_sizes[s]; if (size > NT) size = NT;
        const float* eWb = encW + (size_t)s * NT * NL;
        float* outb = out + (size_t)s * NT * NL;
        int evt_t = -1, evt_start = 0; float evt_den = 1.f;

        for (; t < size; ++t) {
            float ot = (lane < NL) ? tanhf(eWb[(size_t)t * NL + lane] + sh_hWb[lane]) : -INFINITY;
            float bv = ot; int bi = lane;
            #pragma unroll
            for (int d = 32; d; d >>= 1) {
                float ov = __shfl_xor(bv, d);
                int   oi = __shfl_xor(bi, d);
                if (ov > bv || (ov == bv && oi < bi)) { bv = ov; bi = oi; }
            }
            const int aid = bi;
            if (rh == 0 && lane < NL) outb[(size_t)t * NL + lane] = ot;
            const int issep = sh_issep[aid];
            const int wl_prev = wlen;
            int nw_new;
            if (issep) { npos += 1; nw_new = nw + 1; }
            else       { nw_new = (nw < 1) ? 1 : nw; }
            const int do_l = issep && (nw_new >= 2);
            if (issep && npos >= 2) lpe_pend = plast;
            if (issep) plast = sh_posid[aid];
            wlen = issep ? 1 : wlen + 1;
            nw = nw_new;
            if (do_l) {
                evt_t = t;
                evt_start = (t - wl_prev < 0) ? 0 : (t - wl_prev);
                evt_den = (float)((wl_prev < 1) ? 1 : wl_prev);
                if (lpe_pend >= 0) { lpe_eff = lpe_pend; lpe_pend = -1; }
                ++t;
                break;
            }
        }

        if (lane == 0) {
            sh_scan[0] = evt_t; sh_scan[1] = evt_start;
            sh_scan[2] = __float_as_int(evt_den); sh_scan[3] = lpe_eff;
            if (rh == 0) {
                if (evt_t < 0) {
                    iw[IX_DONE] = 1; ir[IX_DONE] = 1;
                } else {
                    iw[IX_T] = t; iw[IX_WLEN] = wlen; iw[IX_NW] = nw;
                    iw[IX_NPOS] = npos; iw[IX_PLAST] = plast;
                    iw[IX_LPEP] = lpe_pend; iw[IX_LPEE] = lpe_eff;
                    iw[IX_DONE] = 0;
                }
            }
        }
    } else if (tid >= 64 && tid < 352) {
        // ---- waves 1-5: W_hh * h half (rows contiguous float4) ----
        const int u = tid - 64;
        const int ci = u / 96, rho = u - ci * 96;     // 3 k-chunks x 96 rows
        const float4* wp = (const float4*)(SLw + (size_t)rho * NE + NH + ci * 128);
        const float4* xp = (const float4*)(sh_h + ci * 128);
        float4 acc = {0.f, 0.f, 0.f, 0.f};
        #pragma unroll
        for (int q = 0; q < 32; ++q) {
            float4 w = wp[q], x = xp[q];
            acc.x += w.x * x.x; acc.y += w.y * x.y;
            acc.z += w.z * x.z; acc.w += w.w * x.w;
        }
        sh_ph[ci * 96 + rho] = (acc.x + acc.y) + (acc.z + acc.w);
    }
    __syncthreads();

    const int evt_t = sh_scan[0];
    if (evt_t < 0) return;
    const int evt_start = sh_scan[1];
    const float evt_den = __int_as_float(sh_scan[2]);
    const int lpe_eff = sh_scan[3];

    // ---- xcat lwp half ----
    {
        const int j = tid;
        float avg = (pcb[(size_t)evt_t * NH + j] - pcb[(size_t)evt_start * NH + j]) / evt_den;
        float pv = (lpe_eff >= 0) ? pew[lpe_eff * NH + j] : 0.f;
        sh_x[j] = tanhf(pv + avg + b_cmb[j]);
    }
    __syncthreads();

    // ---- x-half matvec: rows contiguous float4 ----
    {
        const int kq = tid / 96, rho = tid - kq * 96;
        const float4* wp = (const float4*)(SLw + (size_t)rho * NE + kq * 96);
        const float4* xp = (const float4*)(sh_x + kq * 96);
        float4 acc = {0.f, 0.f, 0.f, 0.f};
        #pragma unroll
        for (int q = 0; q < 24; ++q) {
            float4 w = wp[q], x = xp[q];
            acc.x += w.x * x.x; acc.y += w.y * x.y;
            acc.z += w.z * x.z; acc.w += w.w * x.w;
        }
        sh_part[tid] = (acc.x + acc.y) + (acc.z + acc.w);
    }
    __syncthreads();

    if (tid < RS) {
        const int gate = tid / JS, jj = tid % JS;
        const int grow = gate * NH + rh * JS + jj;
        sh_g[tid] = (((sh_part[tid] + sh_part[96 + tid])
                    + (sh_part[192 + tid] + sh_part[288 + tid]))
                   + ((sh_ph[tid] + sh_ph[96 + tid]) + sh_ph[192 + tid]))
                  + bsum[grow];
    }
    __syncthreads();
    if (tid < JS) {
        float gi = sh_g[tid], gf = sh_g[JS + tid];
        float gg = sh_g[2 * JS + tid], go = sh_g[3 * JS + tid];
        float c2 = sigmf(gf) * creg + sigmf(gi) * tanhf(gg);
        float h2 = sigmf(go) * tanhf(c2);
        cst[rh * JS + tid] = c2;
        h_w[rh * JS + tid] = h2;
        sh_h2[tid] = h2;
    }
    __syncthreads();
    if (tid < NL) {
        const float* wr = W_lin + (size_t)tid * 1152 + rh * JS;
        float a = 0.f;
        #pragma unroll
        for (int k = 0; k < JS; ++k) a += wr[k] * sh_h2[k];
        hWbp_w[rh * 36 + tid] = a;
    }
}

// ---- k_finish: guaranteed completion of any sequence past ROUNDS events ---
// One block per sequence; local full matvec; expected case: all DONE -> exit.
__global__ __launch_bounds__(384) void k_finish(
    const int* __restrict__ char_sizes,
    const int* __restrict__ label_is_sep, const int* __restrict__ label_pos_id,
    const float* __restrict__ W_lin, const float* __restrict__ b_lin,
    const float* __restrict__ b_cmb, float* __restrict__ ws,
    float* __restrict__ out) {

    const int s = blockIdx.x, tid = threadIdx.x;
    const int lane = tid & 63, wave = tid >> 6;
    float* stf = ws + OFF_STATE + (size_t)s * ST_STRIDE;
    int* ii = (int*)stf;                       // slot 0 (ROUNDS even)
    if (ii[IX_DONE]) return;

    const float* SLT  = ws + OFF_SL;
    const float* pew  = ws + OFF_PEW;
    const float* bsum = ws + OFF_BS;
    const float* pcb  = ws + OFF_PC + (size_t)s * 1025 * NH;
    const float* eWb  = ws + OFF_ENCW + (size_t)s * NT * NL;
    float* outb = out + (size_t)s * NT * NL;

    __shared__ __align__(16) float sh_h[NH];
    __shared__ __align__(16) float sh_x[NH];
    __shared__ float sh_red[264], sh_hWb[40];
    __shared__ int sh_issep[NL], sh_posid[NL], sh_scan[8];

    sh_h[tid] = stf[SX_H + tid];               // slot-0 h
    float creg = stf[SX_C + tid];              // j = tid
    if (tid < NL) { sh_issep[tid] = label_is_sep[tid]; sh_posid[tid] = label_pos_id[tid]; }
    int t = ii[IX_T], wlen = ii[IX_WLEN], nw = ii[IX_NW], npos = ii[IX_NPOS],
        plast = ii[IX_PLAST], lpe_pend = ii[IX_LPEP], lpe_eff = ii[IX_LPEE];
    int size = char_sizes[s]; if (size > NT) size = NT;
    __syncthreads();

    for (int iter = 0; iter < 1100; ++iter) {
        // hWb = b_lin + W_lin[:, :384] @ sh_h
        if (tid < 264) {
            const int l = tid >> 3, p = tid & 7;
            const float* wr = W_lin + (size_t)l * 1152 + p * 48;
            const float* hp = sh_h + p * 48;
            float a = 0.f;
            #pragma unroll
            for (int k = 0; k < 48; ++k) a += wr[k] * hp[k];
            sh_red[tid] = a;
        }
        __syncthreads();
        if (tid < NL) {
            float q = b_lin[tid];
            #pragma unroll
            for (int p = 0; p < 8; ++p) q += sh_red[tid * 8 + p];
            sh_hWb[tid] = q;
        }
        __syncthreads();

        // scan (wave 0)
        if (wave == 0) {
            int evt_t = -1, evt_start = 0; float evt_den = 1.f;
            for (; t < size; ++t) {
                float ot = (lane < NL) ? tanhf(eWb[(size_t)t * NL + lane] + sh_hWb[lane]) : -INFINITY;
                float bv = ot; int bi = lane;
                #pragma unroll
                for (int d = 32; d; d >>= 1) {
                    float ov = __shfl_xor(bv, d);
                    int   oi = __shfl_xor(bi, d);
                    if (ov > bv || (ov == bv && oi < bi)) { bv = ov; bi = oi; }
                }
                const int aid = bi;
                if (lane < NL) outb[(size_t)t * NL + lane] = ot;
                const int issep = sh_issep[aid];
                const int wl_prev = wlen;
                int nw_new;
                if (issep) { npos += 1; nw_new = nw + 1; }
                else       { nw_new = (nw < 1) ? 1 : nw; }
                const int do_l = issep && (nw_new >= 2);
                if (issep && npos >= 2) lpe_pend = plast;
                if (issep) plast = sh_posid[aid];
                wlen = issep ? 1 : wlen + 1;
                nw = nw_new;
                if (do_l) {
                    evt_t = t;
                    evt_start = (t - wl_prev < 0) ? 0 : (t - wl_prev);
                    evt_den = (float)((wl_prev < 1) ? 1 : wl_prev);
                    if (lpe_pend >= 0) { lpe_eff = lpe_pend; lpe_pend = -1; }
                    ++t;
                    break;
                }
            }
            if (lane == 0) {
                sh_scan[0] = evt_t; sh_scan[1] = evt_start;
                sh_scan[2] = __float_as_int(evt_den); sh_scan[3] = lpe_eff;
            }
        }
        __syncthreads();
        const int evt_t = sh_scan[0];
        if (evt_t < 0) break;
        const int evt_start = sh_scan[1];
        const float evt_den = __int_as_float(sh_scan[2]);
        const int lpe_e = sh_scan[3];

        // xcat lwp half
        {
            const int j = tid;
            float avg = (pcb[(size_t)evt_t * NH + j] - pcb[(size_t)evt_start * NH + j]) / evt_den;
            float pv = (lpe_e >= 0) ? pew[lpe_e * NH + j] : 0.f;
            sh_x[j] = tanhf(pv + avg + b_cmb[j]);
        }
        __syncthreads();

        // full matvec: thread tid owns j = tid, all 4 gates
        const int sl = tid / JS, jj = tid - sl * JS;
        const float* base = SLT + (size_t)sl * (RS * NE);
        float gv[4];
        #pragma unroll
        for (int g4 = 0; g4 < 4; ++g4) {
            const float4* wp = (const float4*)(base + (size_t)(g4 * JS + jj) * NE);
            const float4* xp = (const float4*)sh_x;
            const float4* hp = (const float4*)sh_h;
            float4 acc = {0.f, 0.f, 0.f, 0.f};
            #pragma unroll 8
            for (int q = 0; q < 96; ++q) {
                float4 w = wp[q], x = xp[q];
                acc.x += w.x * x.x; acc.y += w.y * x.y;
                acc.z += w.z * x.z; acc.w += w.w * x.w;
            }
            #pragma unroll 8
            for (int q = 0; q < 96; ++q) {
                float4 w = wp[96 + q], h = hp[q];
                acc.x += w.x * h.x; acc.y += w.y * h.y;
                acc.z += w.z * h.z; acc.w += w.w * h.w;
            }
            gv[g4] = (acc.x + acc.y) + (acc.z + acc.w) + bsum[g4 * NH + tid];
        }
        float c2 = sigmf(gv[1]) * creg + sigmf(gv[0]) * tanhf(gv[2]);
        float h2 = sigmf(gv[3]) * tanhf(c2);
        creg = c2;
        __syncthreads();
        sh_h[tid] = h2;
        __syncthreads();
    }
}

// ---- parallel log-softmax -------------------------------------------------
__global__ void k_post(float* __restrict__ out) {
    int row = blockIdx.x * 4 + (threadIdx.x >> 6);
    int lane = threadIdx.x & 63;
    if (row >= NB * NT) return;
    float* p = out + (size_t)row * NL;
    float x = (lane < NL) ? p[lane] : -INFINITY;
    float m = x;
    #pragma unroll
    for (int d = 32; d; d >>= 1) m = fmaxf(m, __shfl_xor(m, d));
    float e = (lane < NL) ? expf(x - m) : 0.f;
    float su = e;
    #pragma unroll
    for (int d = 32; d; d >>= 1) su += __shfl_xor(su, d);
    if (lane < NL) p[lane] = (x - m) - logf(su);
}

extern "C" void kernel_launch(void* const* d_in, const int* in_sizes, int n_in,
                              void* d_out, int out_size, void* d_ws, size_t ws_size,
                              hipStream_t stream) {
    const float* enc          = (const float*)d_in[0];
    const int*   char_sizes   = (const int*)d_in[1];
    const int*   label_is_sep = (const int*)d_in[2];
    const int*   label_pos_id = (const int*)d_in[3];
    const float* posEmb       = (const float*)d_in[4];
    const float* W_ih         = (const float*)d_in[5];
    const float* W_hh         = (const float*)d_in[6];
    const float* b_ih         = (const float*)d_in[7];
    const float* b_hh         = (const float*)d_in[8];
    const float* W_lin        = (const float*)d_in[9];
    const float* b_lin        = (const float*)d_in[10];
    const float* W_cmb        = (const float*)d_in[11];
    const float* b_cmb        = (const float*)d_in[12];
    float* out = (float*)d_out;
    float* ws  = (float*)d_ws;

    hipLaunchKernelGGL(k_prep, dim3(1024), dim3(256), 0, stream,
                       W_ih, W_hh, W_cmb, posEmb, ws);
    hipLaunchKernelGGL(k_encw, dim3((NB * NT * NL + 255) / 256), dim3(256), 0, stream,
                       enc, W_lin, ws);
    hipLaunchKernelGGL(k_encCmb, dim3(1024), dim3(384), 0, stream, enc, W_cmb, ws);
    hipLaunchKernelGGL(k_prefix, dim3((NB * NH + 255) / 256), dim3(256), 0, stream, ws);
    hipLaunchKernelGGL(k_init, dim3(1), dim3(1024), 0, stream,
                       b_ih, b_hh, W_lin, b_lin, ws);
    hipLaunchKernelGGL(k_fill, dim3((NB * NT * NL + 255) / 256), dim3(256), 0, stream, out);

    for (int r = 0; r < ROUNDS; ++r) {
        hipLaunchKernelGGL(k_round, dim3(256), dim3(384), 0, stream,
                           char_sizes, label_is_sep, label_pos_id,
                           W_lin, b_lin, b_cmb, ws, out, r & 1);
    }
    hipLaunchKernelGGL(k_finish, dim3(NB), dim3(384), 0, stream,
                       char_sizes, label_is_sep, label_pos_id,
                       W_lin, b_lin, b_cmb, ws, out);

    hipLaunchKernelGGL(k_post, dim3((NB * NT + 3) / 4), dim3(256), 0, stream, out);
}

// Round 12
// 6271.863 us; speedup vs baseline: 1.4008x; 1.4008x over previous
//
#include <hip/hip_runtime.h>
#include <math.h>

// ---------------------------------------------------------------------------
// Decoder_21371757265153 — v12 = v10 k_round (k-major, coalesced weight
// stream; PROVEN 6.90 ms) + ROUNDS 640 + k_finish fallback (from v11) +
// one barrier merged out of the epilogue.
// Post-mortem of v11 (8.79 ms): transposed SLT[row][k] made each lane read a
// row 3 KB apart -> 64 cache lines per wave load (coalescing destroyed).
// k-major SL[sl][k][rho] with lane=rho is consecutive-4B coalesced.
// Measured context: v8 7.39 / v9 grid.sync 45.7 (abandoned) / v10 6.90 /
// v11 8.79. E_max inferred ~445 events.
// ---------------------------------------------------------------------------

namespace {
constexpr int NB = 16;
constexpr int NT = 1024;
constexpr int NE = 768;
constexpr int NH = 384;
constexpr int NL = 33;
constexpr int ROUNDS = 640;    // even => final state in slot 0 for k_finish
constexpr int NSLICE = 16;
constexpr int JS = 24;
constexpr int RS = 96;

constexpr size_t OFF_SL   = 0;                         // SL[sl][k][rho]
constexpr size_t N_SL     = (size_t)NSLICE * NE * RS;  // 1179648
constexpr size_t OFF_PEW  = OFF_SL + N_SL;
constexpr size_t N_PEW    = 32 * NH;
constexpr size_t OFF_ENCW = OFF_PEW + N_PEW;
constexpr size_t N_ENCW   = (size_t)NB * NT * NL;
constexpr size_t OFF_BS   = OFF_ENCW + N_ENCW;
constexpr size_t OFF_PC   = OFF_BS + 2048;
constexpr size_t N_PC     = (size_t)NB * 1025 * NH;
constexpr size_t OFF_STATE = OFF_PC + N_PC;
constexpr size_t ST_STRIDE = 4096;
constexpr int SX_HWBP = 64;    // 2 slots x [16][36]
constexpr int SX_H    = 1280;  // 2 slots x 512
constexpr int SX_C    = 2432;  // 384
constexpr int IX_T = 0, IX_WLEN = 1, IX_NW = 2, IX_NPOS = 3, IX_PLAST = 4,
              IX_LPEP = 5, IX_LPEE = 6, IX_DONE = 7;
}

__device__ __forceinline__ float sigmf(float x) { return 1.0f / (1.0f + expf(-x)); }

// ---- SL[sl][k][rho] (k-major, lane-coalesced) + posEmbW -------------------
// rho = gate*24+jj -> global row = gate*384 + sl*24 + jj
__global__ void k_prep(const float* __restrict__ W_ih, const float* __restrict__ W_hh,
                       const float* __restrict__ W_cmb, const float* __restrict__ posEmb,
                       float* __restrict__ ws) {
    float* SL = ws + OFF_SL;
    float* pw = ws + OFF_PEW;
    const int n1 = (int)N_SL, n2 = (int)N_PEW;
    for (int i = blockIdx.x * blockDim.x + threadIdx.x; i < n1 + n2;
         i += gridDim.x * blockDim.x) {
        if (i < n1) {
            int sl = i / (NE * RS), rem = i % (NE * RS);
            int k = rem / RS, rho = rem % RS;
            int gate = rho / JS, jj = rho % JS;
            int grow = gate * NH + sl * JS + jj;
            SL[i] = (k < NH) ? W_ih[(size_t)grow * NH + k]
                             : W_hh[(size_t)grow * NH + (k - NH)];
        } else {
            int j3 = i - n1;
            int p = j3 / NH, j = j3 % NH;
            const float* pe = posEmb + p * 128;
            const float* wr = W_cmb + (size_t)j * 896;
            float a = 0.f;
            #pragma unroll 4
            for (int k = 0; k < 128; ++k) a += pe[k] * wr[k];
            pw[j3] = a;
        }
    }
}

// ---- encW[bt][l] = enc[bt,:] @ W_lin[l, 384:] -----------------------------
__global__ void k_encw(const float* __restrict__ enc, const float* __restrict__ W_lin,
                       float* __restrict__ ws) {
    float* encW = ws + OFF_ENCW;
    int gid = blockIdx.x * 256 + threadIdx.x;
    if (gid >= NB * NT * NL) return;
    int bt = gid / NL, l = gid % NL;
    const float4* e4 = (const float4*)(enc + (size_t)bt * NE);
    const float4* w4 = (const float4*)(W_lin + (size_t)l * 1152 + NH);
    float a0 = 0, a1 = 0, a2 = 0, a3 = 0;
    for (int k = 0; k < NE / 4; ++k) {
        float4 e = e4[k], w = w4[k];
        a0 += e.x * w.x; a1 += e.y * w.y; a2 += e.z * w.z; a3 += e.w * w.w;
    }
    encW[gid] = (a0 + a1) + (a2 + a3);
}

// ---- pc[b][t][j] = enc[b,t,:] @ W_cmb[j,128:]  (pre-prefix) ---------------
__global__ void k_encCmb(const float* __restrict__ enc, const float* __restrict__ W_cmb,
                         float* __restrict__ ws) {
    __shared__ float tile[16][NE];
    float* pc = ws + OFF_PC;
    int blk = blockIdx.x;
    int b = blk >> 6;
    int t0 = (blk & 63) * 16;
    for (int i = threadIdx.x; i < 16 * NE; i += 384) {
        int row = i / NE, k = i % NE;
        tile[row][k] = enc[((size_t)(b * NT + t0 + row)) * NE + k];
    }
    __syncthreads();
    int j = threadIdx.x;
    const float4* w4 = (const float4*)(W_cmb + (size_t)j * 896 + 128);
    float acc[16];
    #pragma unroll
    for (int r = 0; r < 16; ++r) acc[r] = 0.f;
    for (int q = 0; q < NE / 4; ++q) {
        float4 w = w4[q];
        #pragma unroll
        for (int r = 0; r < 16; ++r) {
            acc[r] += w.x * tile[r][q * 4] + w.y * tile[r][q * 4 + 1]
                    + w.z * tile[r][q * 4 + 2] + w.w * tile[r][q * 4 + 3];
        }
    }
    #pragma unroll
    for (int r = 0; r < 16; ++r)
        pc[((size_t)b * 1025 + t0 + r) * NH + j] = acc[r];
}

// ---- in-place exclusive prefix over t per (b,j) ---------------------------
__global__ void k_prefix(float* __restrict__ ws) {
    float* pc = ws + OFF_PC;
    int id = blockIdx.x * 256 + threadIdx.x;
    if (id >= NB * NH) return;
    int b = id / NH, j = id % NH;
    float* p = pc + ((size_t)b * 1025) * NH + j;
    float s = 0.f;
    for (int t = 0; t < NT; ++t) {
        float x = p[(size_t)t * NH];
        p[(size_t)t * NH] = s;
        s += x;
    }
    p[(size_t)NT * NH] = s;
}

// ---- init: slot-0 state, bsum ---------------------------------------------
__global__ void k_init(const float* __restrict__ b_ih, const float* __restrict__ b_hh,
                       const float* __restrict__ W_lin, const float* __restrict__ b_lin,
                       float* __restrict__ ws) {
    __shared__ float shh[NH], shc[NH], shw[NL];
    int tid = threadIdx.x;
    if (tid < NH) {
        float gi = b_ih[tid] + b_hh[tid];
        float gg = b_ih[2 * NH + tid] + b_hh[2 * NH + tid];
        float go = b_ih[3 * NH + tid] + b_hh[3 * NH + tid];
        float c = sigmf(gi) * tanhf(gg);
        float h = sigmf(go) * tanhf(c);
        shh[tid] = h; shc[tid] = c;
    }
    __syncthreads();
    if (tid < NL) {
        float a = b_lin[tid];
        for (int k = 0; k < NH; ++k) a += W_lin[(size_t)tid * 1152 + k] * shh[k];
        shw[tid] = a;
    }
    for (int i = tid; i < 4 * NH; i += 1024) ws[OFF_BS + i] = b_ih[i] + b_hh[i];
    __syncthreads();
    for (int s = 0; s < NB; ++s) {
        float* stf = ws + OFF_STATE + (size_t)s * ST_STRIDE;
        int* ii = (int*)stf;
        if (tid < 16) ii[tid] = (tid == IX_LPEP || tid == IX_LPEE) ? -1 : 0;
        if (tid >= 32 && tid < 32 + 576) {
            int i2 = tid - 32, r = i2 / 36, l = i2 % 36;
            stf[SX_HWBP + i2] = (r == 0 && l < NL) ? (shw[l] - b_lin[l]) : 0.f;
        }
        if (tid < NH) { stf[SX_H + tid] = shh[tid]; stf[SX_C + tid] = shc[tid]; }
    }
}

// ---- zero output ----------------------------------------------------------
__global__ void k_fill(float* __restrict__ out) {
    int i = blockIdx.x * 256 + threadIdx.x;
    if (i < NB * NT * NL) out[i] = 0.f;
}

// ---- k_round: scan (wave 0) || W_hh*h half-matvec (v10-proven layout) -----
__global__ __launch_bounds__(384) void k_round(
    const int* __restrict__ char_sizes,
    const int* __restrict__ label_is_sep, const int* __restrict__ label_pos_id,
    const float* __restrict__ W_lin, const float* __restrict__ b_lin,
    const float* __restrict__ b_cmb, float* __restrict__ ws,
    float* __restrict__ out, const int slot) {

    const int bid = blockIdx.x;
    const int s = bid >> 4;
    const int rh = bid & 15;
    const int tid = threadIdx.x;
    const int lane = tid & 63;
    const int wave = tid >> 6;

    float* stf = ws + OFF_STATE + (size_t)s * ST_STRIDE;
    int* ir = (int*)stf + slot * 16;
    int* iw = (int*)stf + (slot ^ 1) * 16;
    if (ir[IX_DONE]) return;

    const float* hWbp_r = stf + SX_HWBP + slot * 576;
    float*       hWbp_w = stf + SX_HWBP + (slot ^ 1) * 576;
    const float* h_r    = stf + SX_H + slot * 512;
    float*       h_w    = stf + SX_H + (slot ^ 1) * 512;
    float*       cst    = stf + SX_C;

    const float* SLw  = ws + OFF_SL + (size_t)rh * (NE * RS);
    const float* pew  = ws + OFF_PEW;
    const float* encW = ws + OFF_ENCW;
    const float* bsum = ws + OFF_BS;
    const float* pcb  = ws + OFF_PC + (size_t)s * 1025 * NH;

    __shared__ float sh_hWb[40], sh_h[NH], sh_x[NH], sh_part[384], sh_ph[288];
    __shared__ float sh_h2[JS];
    __shared__ int sh_issep[NL], sh_posid[NL], sh_scan[8];

    // prologue: h into LDS (for h-half waves), c into registers
    sh_h[tid] = h_r[tid];
    float creg = (tid < JS) ? cst[rh * JS + tid] : 0.f;
    __syncthreads();

    if (wave == 0) {
        // ---- wave 0: tables + hWb + scan ----
        if (lane < NL) {
            sh_issep[lane] = label_is_sep[lane];
            sh_posid[lane] = label_pos_id[lane];
            float a = b_lin[lane];
            #pragma unroll
            for (int i = 0; i < 16; ++i) a += hWbp_r[i * 36 + lane];
            sh_hWb[lane] = a;
        }
        asm volatile("" ::: "memory");

        int t = ir[IX_T], wlen = ir[IX_WLEN], nw = ir[IX_NW], npos = ir[IX_NPOS],
            plast = ir[IX_PLAST], lpe_pend = ir[IX_LPEP], lpe_eff = ir[IX_LPEE];
        int size = char_sizes[s]; if (size > NT) size = NT;
        const float* eWb = encW + (size_t)s * NT * NL;
        float* outb = out + (size_t)s * NT * NL;
        int evt_t = -1, evt_start = 0; float evt_den = 1.f;

        for (; t < size; ++t) {
            float ot = (lane < NL) ? tanhf(eWb[(size_t)t * NL + lane] + sh_hWb[lane]) : -INFINITY;
            float bv = ot; int bi = lane;
            #pragma unroll
            for (int d = 32; d; d >>= 1) {
                float ov = __shfl_xor(bv, d);
                int   oi = __shfl_xor(bi, d);
                if (ov > bv || (ov == bv && oi < bi)) { bv = ov; bi = oi; }
            }
            const int aid = bi;
            if (rh == 0 && lane < NL) outb[(size_t)t * NL + lane] = ot;
            const int issep = sh_issep[aid];
            const int wl_prev = wlen;
            int nw_new;
            if (issep) { npos += 1; nw_new = nw + 1; }
            else       { nw_new = (nw < 1) ? 1 : nw; }
            const int do_l = issep && (nw_new >= 2);
            if (issep && npos >= 2) lpe_pend = plast;
            if (issep) plast = sh_posid[aid];
            wlen = issep ? 1 : wlen + 1;
            nw = nw_new;
            if (do_l) {
                evt_t = t;
                evt_start = (t - wl_prev < 0) ? 0 : (t - wl_prev);
                evt_den = (float)((wl_prev < 1) ? 1 : wl_prev);
                if (lpe_pend >= 0) { lpe_eff = lpe_pend; lpe_pend = -1; }
                ++t;
                break;
            }
        }

        if (lane == 0) {
            sh_scan[0] = evt_t; sh_scan[1] = evt_start;
            sh_scan[2] = __float_as_int(evt_den); sh_scan[3] = lpe_eff;
            if (rh == 0) {
                if (evt_t < 0) {
                    iw[IX_DONE] = 1; ir[IX_DONE] = 1;
                } else {
                    iw[IX_T] = t; iw[IX_WLEN] = wlen; iw[IX_NW] = nw;
                    iw[IX_NPOS] = npos; iw[IX_PLAST] = plast;
                    iw[IX_LPEP] = lpe_pend; iw[IX_LPEE] = lpe_eff;
                    iw[IX_DONE] = 0;
                }
            }
        }
    } else if (tid >= 64 && tid < 352) {
        // ---- waves 1-5: W_hh * h half (k-major, lane-coalesced) ----
        const int u = tid - 64;
        const int ci = u / 96, rho = u - ci * 96;     // 3 k-chunks x 96 rows
        const float* wp = SLw + (size_t)(NH + ci * 128) * RS + rho;
        const float* xp = sh_h + ci * 128;
        float a0 = 0.f, a1 = 0.f, a2 = 0.f, a3 = 0.f;
        #pragma unroll 8
        for (int k = 0; k < 128; k += 4) {
            a0 += wp[(size_t)(k + 0) * RS] * xp[k + 0];
            a1 += wp[(size_t)(k + 1) * RS] * xp[k + 1];
            a2 += wp[(size_t)(k + 2) * RS] * xp[k + 2];
            a3 += wp[(size_t)(k + 3) * RS] * xp[k + 3];
        }
        sh_ph[ci * 96 + rho] = (a0 + a1) + (a2 + a3);
    }
    __syncthreads();

    const int evt_t = sh_scan[0];
    if (evt_t < 0) return;
    const int evt_start = sh_scan[1];
    const float evt_den = __int_as_float(sh_scan[2]);
    const int lpe_eff = sh_scan[3];

    // ---- xcat lwp half ----
    {
        const int j = tid;
        float avg = (pcb[(size_t)evt_t * NH + j] - pcb[(size_t)evt_start * NH + j]) / evt_den;
        float pv = (lpe_eff >= 0) ? pew[lpe_eff * NH + j] : 0.f;
        sh_x[j] = tanhf(pv + avg + b_cmb[j]);
    }
    __syncthreads();

    // ---- x-half matvec (k-major, lane-coalesced) ----
    {
        const int kq = tid / 96, rho = tid - kq * 96;
        const float* wp = SLw + (size_t)(kq * 96) * RS + rho;
        const float* xp = sh_x + kq * 96;
        float a0 = 0.f, a1 = 0.f, a2 = 0.f, a3 = 0.f;
        #pragma unroll 8
        for (int k = 0; k < 96; k += 4) {
            a0 += wp[(size_t)(k + 0) * RS] * xp[k + 0];
            a1 += wp[(size_t)(k + 1) * RS] * xp[k + 1];
            a2 += wp[(size_t)(k + 2) * RS] * xp[k + 2];
            a3 += wp[(size_t)(k + 3) * RS] * xp[k + 3];
        }
        sh_part[tid] = (a0 + a1) + (a2 + a3);
    }
    __syncthreads();

    // ---- merged gate-sum + gate-apply (tid<24; bit-exact association) ----
    if (tid < JS) {
        float gv[4];
        #pragma unroll
        for (int g4 = 0; g4 < 4; ++g4) {
            const int rho = g4 * JS + tid;
            const int grow = g4 * NH + rh * JS + tid;
            gv[g4] = (((sh_part[rho] + sh_part[96 + rho])
                     + (sh_part[192 + rho] + sh_part[288 + rho]))
                    + ((sh_ph[rho] + sh_ph[96 + rho]) + sh_ph[192 + rho]))
                   + bsum[grow];
        }
        float c2 = sigmf(gv[1]) * creg + sigmf(gv[0]) * tanhf(gv[2]);
        float h2 = sigmf(gv[3]) * tanhf(c2);
        cst[rh * JS + tid] = c2;
        h_w[rh * JS + tid] = h2;
        sh_h2[tid] = h2;
    }
    __syncthreads();
    if (tid < NL) {
        const float* wr = W_lin + (size_t)tid * 1152 + rh * JS;
        float a = 0.f;
        #pragma unroll
        for (int k = 0; k < JS; ++k) a += wr[k] * sh_h2[k];
        hWbp_w[rh * 36 + tid] = a;
    }
}

// ---- k_finish: guaranteed completion past ROUNDS events (expected no-op) --
__global__ __launch_bounds__(384) void k_finish(
    const int* __restrict__ char_sizes,
    const int* __restrict__ label_is_sep, const int* __restrict__ label_pos_id,
    const float* __restrict__ W_lin, const float* __restrict__ b_lin,
    const float* __restrict__ b_cmb, float* __restrict__ ws,
    float* __restrict__ out) {

    const int s = blockIdx.x, tid = threadIdx.x;
    const int lane = tid & 63, wave = tid >> 6;
    float* stf = ws + OFF_STATE + (size_t)s * ST_STRIDE;
    int* ii = (int*)stf;                       // slot 0 (ROUNDS even)
    if (ii[IX_DONE]) return;

    const float* SL   = ws + OFF_SL;
    const float* pew  = ws + OFF_PEW;
    const float* bsum = ws + OFF_BS;
    const float* pcb  = ws + OFF_PC + (size_t)s * 1025 * NH;
    const float* eWb  = ws + OFF_ENCW + (size_t)s * NT * NL;
    float* outb = out + (size_t)s * NT * NL;

    __shared__ float sh_h[NH], sh_x[NH], sh_red[264], sh_hWb[40];
    __shared__ int sh_issep[NL], sh_posid[NL], sh_scan[8];

    sh_h[tid] = stf[SX_H + tid];               // slot-0 h
    float creg = stf[SX_C + tid];
    if (tid < NL) { sh_issep[tid] = label_is_sep[tid]; sh_posid[tid] = label_pos_id[tid]; }
    int t = ii[IX_T], wlen = ii[IX_WLEN], nw = ii[IX_NW], npos = ii[IX_NPOS],
        plast = ii[IX_PLAST], lpe_pend = ii[IX_LPEP], lpe_eff = ii[IX_LPEE];
    int size = char_sizes[s]; if (size > NT) size = NT;
    __syncthreads();

    for (int iter = 0; iter < 1100; ++iter) {
        if (tid < 264) {
            const int l = tid >> 3, p = tid & 7;
            const float* wr = W_lin + (size_t)l * 1152 + p * 48;
            const float* hp = sh_h + p * 48;
            float a = 0.f;
            #pragma unroll
            for (int k = 0; k < 48; ++k) a += wr[k] * hp[k];
            sh_red[tid] = a;
        }
        __syncthreads();
        if (tid < NL) {
            float q = b_lin[tid];
            #pragma unroll
            for (int p = 0; p < 8; ++p) q += sh_red[tid * 8 + p];
            sh_hWb[tid] = q;
        }
        __syncthreads();

        if (wave == 0) {
            int evt_t = -1, evt_start = 0; float evt_den = 1.f;
            for (; t < size; ++t) {
                float ot = (lane < NL) ? tanhf(eWb[(size_t)t * NL + lane] + sh_hWb[lane]) : -INFINITY;
                float bv = ot; int bi = lane;
                #pragma unroll
                for (int d = 32; d; d >>= 1) {
                    float ov = __shfl_xor(bv, d);
                    int   oi = __shfl_xor(bi, d);
                    if (ov > bv || (ov == bv && oi < bi)) { bv = ov; bi = oi; }
                }
                const int aid = bi;
                if (lane < NL) outb[(size_t)t * NL + lane] = ot;
                const int issep = sh_issep[aid];
                const int wl_prev = wlen;
                int nw_new;
                if (issep) { npos += 1; nw_new = nw + 1; }
                else       { nw_new = (nw < 1) ? 1 : nw; }
                const int do_l = issep && (nw_new >= 2);
                if (issep && npos >= 2) lpe_pend = plast;
                if (issep) plast = sh_posid[aid];
                wlen = issep ? 1 : wlen + 1;
                nw = nw_new;
                if (do_l) {
                    evt_t = t;
                    evt_start = (t - wl_prev < 0) ? 0 : (t - wl_prev);
                    evt_den = (float)((wl_prev < 1) ? 1 : wl_prev);
                    if (lpe_pend >= 0) { lpe_eff = lpe_pend; lpe_pend = -1; }
                    ++t;
                    break;
                }
            }
            if (lane == 0) {
                sh_scan[0] = evt_t; sh_scan[1] = evt_start;
                sh_scan[2] = __float_as_int(evt_den); sh_scan[3] = lpe_eff;
            }
        }
        __syncthreads();
        const int evt_t = sh_scan[0];
        if (evt_t < 0) break;
        const int evt_start = sh_scan[1];
        const float evt_den = __int_as_float(sh_scan[2]);
        const int lpe_e = sh_scan[3];

        {
            const int j = tid;
            float avg = (pcb[(size_t)evt_t * NH + j] - pcb[(size_t)evt_start * NH + j]) / evt_den;
            float pv = (lpe_e >= 0) ? pew[lpe_e * NH + j] : 0.f;
            sh_x[j] = tanhf(pv + avg + b_cmb[j]);
        }
        __syncthreads();

        // full matvec: thread j=tid, 4 gates; SL[sl][k][rho] k-major
        const int sl = tid / JS, jj = tid - sl * JS;
        const float* base = SL + (size_t)sl * (NE * RS);
        float gv[4];
        #pragma unroll
        for (int g4 = 0; g4 < 4; ++g4) {
            const int rho = g4 * JS + jj;
            const float* wp = base + rho;
            float a0 = 0.f, a1 = 0.f;
            for (int k = 0; k < NH; k += 2) {
                a0 += wp[(size_t)k * RS] * sh_x[k];
                a1 += wp[(size_t)(k + 1) * RS] * sh_x[k + 1];
            }
            for (int k = 0; k < NH; k += 2) {
                a0 += wp[(size_t)(NH + k) * RS] * sh_h[k];
                a1 += wp[(size_t)(NH + k + 1) * RS] * sh_h[k + 1];
            }
            gv[g4] = a0 + a1 + bsum[g4 * NH + tid];
        }
        float c2 = sigmf(gv[1]) * creg + sigmf(gv[0]) * tanhf(gv[2]);
        float h2 = sigmf(gv[3]) * tanhf(c2);
        creg = c2;
        __syncthreads();
        sh_h[tid] = h2;
        __syncthreads();
    }
}

// ---- parallel log-softmax -------------------------------------------------
__global__ void k_post(float* __restrict__ out) {
    int row = blockIdx.x * 4 + (threadIdx.x >> 6);
    int lane = threadIdx.x & 63;
    if (row >= NB * NT) return;
    float* p = out + (size_t)row * NL;
    float x = (lane < NL) ? p[lane] : -INFINITY;
    float m = x;
    #pragma unroll
    for (int d = 32; d; d >>= 1) m = fmaxf(m, __shfl_xor(m, d));
    float e = (lane < NL) ? expf(x - m) : 0.f;
    float su = e;
    #pragma unroll
    for (int d = 32; d; d >>= 1) su += __shfl_xor(su, d);
    if (lane < NL) p[lane] = (x - m) - logf(su);
}

extern "C" void kernel_launch(void* const* d_in, const int* in_sizes, int n_in,
                              void* d_out, int out_size, void* d_ws, size_t ws_size,
                              hipStream_t stream) {
    const float* enc          = (const float*)d_in[0];
    const int*   char_sizes   = (const int*)d_in[1];
    const int*   label_is_sep = (const int*)d_in[2];
    const int*   label_pos_id = (const int*)d_in[3];
    const float* posEmb       = (const float*)d_in[4];
    const float* W_ih         = (const float*)d_in[5];
    const float* W_hh         = (const float*)d_in[6];
    const float* b_ih         = (const float*)d_in[7];
    const float* b_hh         = (const float*)d_in[8];
    const float* W_lin        = (const float*)d_in[9];
    const float* b_lin        = (const float*)d_in[10];
    const float* W_cmb        = (const float*)d_in[11];
    const float* b_cmb        = (const float*)d_in[12];
    float* out = (float*)d_out;
    float* ws  = (float*)d_ws;

    hipLaunchKernelGGL(k_prep, dim3(1024), dim3(256), 0, stream,
                       W_ih, W_hh, W_cmb, posEmb, ws);
    hipLaunchKernelGGL(k_encw, dim3((NB * NT * NL + 255) / 256), dim3(256), 0, stream,
                       enc, W_lin, ws);
    hipLaunchKernelGGL(k_encCmb, dim3(1024), dim3(384), 0, stream, enc, W_cmb, ws);
    hipLaunchKernelGGL(k_prefix, dim3((NB * NH + 255) / 256), dim3(256), 0, stream, ws);
    hipLaunchKernelGGL(k_init, dim3(1), dim3(1024), 0, stream,
                       b_ih, b_hh, W_lin, b_lin, ws);
    hipLaunchKernelGGL(k_fill, dim3((NB * NT * NL + 255) / 256), dim3(256), 0, stream, out);

    for (int r = 0; r < ROUNDS; ++r) {
        hipLaunchKernelGGL(k_round, dim3(256), dim3(384), 0, stream,
                           char_sizes, label_is_sep, label_pos_id,
                           W_lin, b_lin, b_cmb, ws, out, r & 1);
    }
    hipLaunchKernelGGL(k_finish, dim3(NB), dim3(384), 0, stream,
                       char_sizes, label_is_sep, label_pos_id,
                       W_lin, b_lin, b_cmb, ws, out);

    hipLaunchKernelGGL(k_post, dim3((NB * NT + 3) / 4), dim3(256), 0, stream, out);
}

// Round 13
// 6091.034 us; speedup vs baseline: 1.4424x; 1.0297x over previous
//
#include <hip/hip_runtime.h>
#include <math.h>

// ---------------------------------------------------------------------------
// Decoder_21371757265153 — v13 = v12 (6.27 ms, PROVEN) with two changes in
// k_round only:
//  (1) float4-over-rho weight loads in BOTH matvec halves (same k-major
//      SL[sl][k][rho] layout; thread (chunk,quad) reads 16B contiguous,
//      384 B/lane-group coalesced, 4x fewer VMEM ops, ~4x bytes in flight).
//      x-half: 16 k-chunks x 24 rho-quads (384 thr); h-half: 12 x 24 (288).
//  (2) prologue load overlap: issue ir/h/c/hWbp loads before the DONE
//      branch so their latencies overlap.
// Context: v8 7.39 / v10 6.90 / v11 8.79 (transposed rows broke coalescing,
// reverted) / v12 6.27. E_max <= 640 proven (absmax 0.0 => k_finish no-op).
// ---------------------------------------------------------------------------

namespace {
constexpr int NB = 16;
constexpr int NT = 1024;
constexpr int NE = 768;
constexpr int NH = 384;
constexpr int NL = 33;
constexpr int ROUNDS = 640;    // even => final state in slot 0 for k_finish
constexpr int NSLICE = 16;
constexpr int JS = 24;
constexpr int RS = 96;

constexpr size_t OFF_SL   = 0;                         // SL[sl][k][rho]
constexpr size_t N_SL     = (size_t)NSLICE * NE * RS;  // 1179648
constexpr size_t OFF_PEW  = OFF_SL + N_SL;
constexpr size_t N_PEW    = 32 * NH;
constexpr size_t OFF_ENCW = OFF_PEW + N_PEW;
constexpr size_t N_ENCW   = (size_t)NB * NT * NL;
constexpr size_t OFF_BS   = OFF_ENCW + N_ENCW;
constexpr size_t OFF_PC   = OFF_BS + 2048;
constexpr size_t N_PC     = (size_t)NB * 1025 * NH;
constexpr size_t OFF_STATE = OFF_PC + N_PC;
constexpr size_t ST_STRIDE = 4096;
constexpr int SX_HWBP = 64;    // 2 slots x [16][36]
constexpr int SX_H    = 1280;  // 2 slots x 512
constexpr int SX_C    = 2432;  // 384
constexpr int IX_T = 0, IX_WLEN = 1, IX_NW = 2, IX_NPOS = 3, IX_PLAST = 4,
              IX_LPEP = 5, IX_LPEE = 6, IX_DONE = 7;
}

__device__ __forceinline__ float sigmf(float x) { return 1.0f / (1.0f + expf(-x)); }

// ---- SL[sl][k][rho] (k-major, lane-coalesced) + posEmbW -------------------
// rho = gate*24+jj -> global row = gate*384 + sl*24 + jj
__global__ void k_prep(const float* __restrict__ W_ih, const float* __restrict__ W_hh,
                       const float* __restrict__ W_cmb, const float* __restrict__ posEmb,
                       float* __restrict__ ws) {
    float* SL = ws + OFF_SL;
    float* pw = ws + OFF_PEW;
    const int n1 = (int)N_SL, n2 = (int)N_PEW;
    for (int i = blockIdx.x * blockDim.x + threadIdx.x; i < n1 + n2;
         i += gridDim.x * blockDim.x) {
        if (i < n1) {
            int sl = i / (NE * RS), rem = i % (NE * RS);
            int k = rem / RS, rho = rem % RS;
            int gate = rho / JS, jj = rho % JS;
            int grow = gate * NH + sl * JS + jj;
            SL[i] = (k < NH) ? W_ih[(size_t)grow * NH + k]
                             : W_hh[(size_t)grow * NH + (k - NH)];
        } else {
            int j3 = i - n1;
            int p = j3 / NH, j = j3 % NH;
            const float* pe = posEmb + p * 128;
            const float* wr = W_cmb + (size_t)j * 896;
            float a = 0.f;
            #pragma unroll 4
            for (int k = 0; k < 128; ++k) a += pe[k] * wr[k];
            pw[j3] = a;
        }
    }
}

// ---- encW[bt][l] = enc[bt,:] @ W_lin[l, 384:] -----------------------------
__global__ void k_encw(const float* __restrict__ enc, const float* __restrict__ W_lin,
                       float* __restrict__ ws) {
    float* encW = ws + OFF_ENCW;
    int gid = blockIdx.x * 256 + threadIdx.x;
    if (gid >= NB * NT * NL) return;
    int bt = gid / NL, l = gid % NL;
    const float4* e4 = (const float4*)(enc + (size_t)bt * NE);
    const float4* w4 = (const float4*)(W_lin + (size_t)l * 1152 + NH);
    float a0 = 0, a1 = 0, a2 = 0, a3 = 0;
    for (int k = 0; k < NE / 4; ++k) {
        float4 e = e4[k], w = w4[k];
        a0 += e.x * w.x; a1 += e.y * w.y; a2 += e.z * w.z; a3 += e.w * w.w;
    }
    encW[gid] = (a0 + a1) + (a2 + a3);
}

// ---- pc[b][t][j] = enc[b,t,:] @ W_cmb[j,128:]  (pre-prefix) ---------------
__global__ void k_encCmb(const float* __restrict__ enc, const float* __restrict__ W_cmb,
                         float* __restrict__ ws) {
    __shared__ float tile[16][NE];
    float* pc = ws + OFF_PC;
    int blk = blockIdx.x;
    int b = blk >> 6;
    int t0 = (blk & 63) * 16;
    for (int i = threadIdx.x; i < 16 * NE; i += 384) {
        int row = i / NE, k = i % NE;
        tile[row][k] = enc[((size_t)(b * NT + t0 + row)) * NE + k];
    }
    __syncthreads();
    int j = threadIdx.x;
    const float4* w4 = (const float4*)(W_cmb + (size_t)j * 896 + 128);
    float acc[16];
    #pragma unroll
    for (int r = 0; r < 16; ++r) acc[r] = 0.f;
    for (int q = 0; q < NE / 4; ++q) {
        float4 w = w4[q];
        #pragma unroll
        for (int r = 0; r < 16; ++r) {
            acc[r] += w.x * tile[r][q * 4] + w.y * tile[r][q * 4 + 1]
                    + w.z * tile[r][q * 4 + 2] + w.w * tile[r][q * 4 + 3];
        }
    }
    #pragma unroll
    for (int r = 0; r < 16; ++r)
        pc[((size_t)b * 1025 + t0 + r) * NH + j] = acc[r];
}

// ---- in-place exclusive prefix over t per (b,j) ---------------------------
__global__ void k_prefix(float* __restrict__ ws) {
    float* pc = ws + OFF_PC;
    int id = blockIdx.x * 256 + threadIdx.x;
    if (id >= NB * NH) return;
    int b = id / NH, j = id % NH;
    float* p = pc + ((size_t)b * 1025) * NH + j;
    float s = 0.f;
    for (int t = 0; t < NT; ++t) {
        float x = p[(size_t)t * NH];
        p[(size_t)t * NH] = s;
        s += x;
    }
    p[(size_t)NT * NH] = s;
}

// ---- init: slot-0 state, bsum ---------------------------------------------
__global__ void k_init(const float* __restrict__ b_ih, const float* __restrict__ b_hh,
                       const float* __restrict__ W_lin, const float* __restrict__ b_lin,
                       float* __restrict__ ws) {
    __shared__ float shh[NH], shc[NH], shw[NL];
    int tid = threadIdx.x;
    if (tid < NH) {
        float gi = b_ih[tid] + b_hh[tid];
        float gg = b_ih[2 * NH + tid] + b_hh[2 * NH + tid];
        float go = b_ih[3 * NH + tid] + b_hh[3 * NH + tid];
        float c = sigmf(gi) * tanhf(gg);
        float h = sigmf(go) * tanhf(c);
        shh[tid] = h; shc[tid] = c;
    }
    __syncthreads();
    if (tid < NL) {
        float a = b_lin[tid];
        for (int k = 0; k < NH; ++k) a += W_lin[(size_t)tid * 1152 + k] * shh[k];
        shw[tid] = a;
    }
    for (int i = tid; i < 4 * NH; i += 1024) ws[OFF_BS + i] = b_ih[i] + b_hh[i];
    __syncthreads();
    for (int s = 0; s < NB; ++s) {
        float* stf = ws + OFF_STATE + (size_t)s * ST_STRIDE;
        int* ii = (int*)stf;
        if (tid < 16) ii[tid] = (tid == IX_LPEP || tid == IX_LPEE) ? -1 : 0;
        if (tid >= 32 && tid < 32 + 576) {
            int i2 = tid - 32, r = i2 / 36, l = i2 % 36;
            stf[SX_HWBP + i2] = (r == 0 && l < NL) ? (shw[l] - b_lin[l]) : 0.f;
        }
        if (tid < NH) { stf[SX_H + tid] = shh[tid]; stf[SX_C + tid] = shc[tid]; }
    }
}

// ---- zero output ----------------------------------------------------------
__global__ void k_fill(float* __restrict__ out) {
    int i = blockIdx.x * 256 + threadIdx.x;
    if (i < NB * NT * NL) out[i] = 0.f;
}

// ---- k_round: scan (wave 0) || W_hh*h half; float4-over-rho streams -------
__global__ __launch_bounds__(384) void k_round(
    const int* __restrict__ char_sizes,
    const int* __restrict__ label_is_sep, const int* __restrict__ label_pos_id,
    const float* __restrict__ W_lin, const float* __restrict__ b_lin,
    const float* __restrict__ b_cmb, float* __restrict__ ws,
    float* __restrict__ out, const int slot) {

    const int bid = blockIdx.x;
    const int s = bid >> 4;
    const int rh = bid & 15;
    const int tid = threadIdx.x;
    const int lane = tid & 63;
    const int wave = tid >> 6;

    float* stf = ws + OFF_STATE + (size_t)s * ST_STRIDE;
    int* ir = (int*)stf + slot * 16;
    int* iw = (int*)stf + (slot ^ 1) * 16;

    const float* hWbp_r = stf + SX_HWBP + slot * 576;
    float*       hWbp_w = stf + SX_HWBP + (slot ^ 1) * 576;
    const float* h_r    = stf + SX_H + slot * 512;
    float*       h_w    = stf + SX_H + (slot ^ 1) * 512;
    float*       cst    = stf + SX_C;

    const float* SLw  = ws + OFF_SL + (size_t)rh * (NE * RS);
    const float* pew  = ws + OFF_PEW;
    const float* encW = ws + OFF_ENCW;
    const float* bsum = ws + OFF_BS;
    const float* pcb  = ws + OFF_PC + (size_t)s * 1025 * NH;

    __shared__ float sh_hWb[40], sh_h[NH], sh_x[NH];
    __shared__ float sh_part[16 * 96];    // x-half partials (16 k-chunks)
    __shared__ float sh_ph[12 * 96];      // h-half partials (12 k-chunks)
    __shared__ float sh_h2[JS];
    __shared__ int sh_issep[NL], sh_posid[NL], sh_scan[8];

    // ---- prologue: issue ALL state loads, then branch (latency overlap) ----
    const int done = ir[IX_DONE];
    const float hval = h_r[tid];
    const float cval = (tid < JS) ? cst[rh * JS + tid] : 0.f;
    float hw = 0.f;
    int isep = 0, pid = 0;
    if (wave == 0 && lane < NL) {
        isep = label_is_sep[lane];
        pid  = label_pos_id[lane];
        hw = b_lin[lane];
        #pragma unroll
        for (int i = 0; i < 16; ++i) hw += hWbp_r[i * 36 + lane];
    }
    if (done) return;
    sh_h[tid] = hval;
    const float creg = cval;
    if (wave == 0 && lane < NL) {
        sh_issep[lane] = isep; sh_posid[lane] = pid; sh_hWb[lane] = hw;
    }
    __syncthreads();

    if (wave == 0) {
        // ---- wave 0: scan ----
        int t = ir[IX_T], wlen = ir[IX_WLEN], nw = ir[IX_NW], npos = ir[IX_NPOS],
            plast = ir[IX_PLAST], lpe_pend = ir[IX_LPEP], lpe_eff = ir[IX_LPEE];
        int size = char_sizes[s]; if (size > NT) size = NT;
        const float* eWb = encW + (size_t)s * NT * NL;
        float* outb = out + (size_t)s * NT * NL;
        int evt_t = -1, evt_start = 0; float evt_den = 1.f;

        for (; t < size; ++t) {
            float ot = (lane < NL) ? tanhf(eWb[(size_t)t * NL + lane] + sh_hWb[lane]) : -INFINITY;
            float bv = ot; int bi = lane;
            #pragma unroll
            for (int d = 32; d; d >>= 1) {
                float ov = __shfl_xor(bv, d);
                int   oi = __shfl_xor(bi, d);
                if (ov > bv || (ov == bv && oi < bi)) { bv = ov; bi = oi; }
            }
            const int aid = bi;
            if (rh == 0 && lane < NL) outb[(size_t)t * NL + lane] = ot;
            const int issep = sh_issep[aid];
            const int wl_prev = wlen;
            int nw_new;
            if (issep) { npos += 1; nw_new = nw + 1; }
            else       { nw_new = (nw < 1) ? 1 : nw; }
            const int do_l = issep && (nw_new >= 2);
            if (issep && npos >= 2) lpe_pend = plast;
            if (issep) plast = sh_posid[aid];
            wlen = issep ? 1 : wlen + 1;
            nw = nw_new;
            if (do_l) {
                evt_t = t;
                evt_start = (t - wl_prev < 0) ? 0 : (t - wl_prev);
                evt_den = (float)((wl_prev < 1) ? 1 : wl_prev);
                if (lpe_pend >= 0) { lpe_eff = lpe_pend; lpe_pend = -1; }
                ++t;
                break;
            }
        }

        if (lane == 0) {
            sh_scan[0] = evt_t; sh_scan[1] = evt_start;
            sh_scan[2] = __float_as_int(evt_den); sh_scan[3] = lpe_eff;
            if (rh == 0) {
                if (evt_t < 0) {
                    iw[IX_DONE] = 1; ir[IX_DONE] = 1;
                } else {
                    iw[IX_T] = t; iw[IX_WLEN] = wlen; iw[IX_NW] = nw;
                    iw[IX_NPOS] = npos; iw[IX_PLAST] = plast;
                    iw[IX_LPEP] = lpe_pend; iw[IX_LPEE] = lpe_eff;
                    iw[IX_DONE] = 0;
                }
            }
        }
    } else if (tid >= 64 && tid < 352) {
        // ---- waves 1-5: W_hh*h half — float4 over rho, 12 chunks x 32 k ----
        const int u = tid - 64;
        const int q = u % 24;          // rho-quad: rho = 4q..4q+3
        const int c = u / 24;          // k-chunk: k in [NH + 32c, NH + 32c + 32)
        const float4* wp = (const float4*)(SLw + (size_t)(NH + c * 32) * RS) + q;
        const float* xp = sh_h + c * 32;
        float4 acc = {0.f, 0.f, 0.f, 0.f};
        #pragma unroll 8
        for (int k = 0; k < 32; ++k) {
            float4 w = wp[(size_t)k * 24];
            float x = xp[k];
            acc.x += w.x * x; acc.y += w.y * x; acc.z += w.z * x; acc.w += w.w * x;
        }
        *(float4*)&sh_ph[c * 96 + q * 4] = acc;
    }
    __syncthreads();

    const int evt_t = sh_scan[0];
    if (evt_t < 0) return;
    const int evt_start = sh_scan[1];
    const float evt_den = __int_as_float(sh_scan[2]);
    const int lpe_eff = sh_scan[3];

    // ---- xcat lwp half ----
    {
        const int j = tid;
        float avg = (pcb[(size_t)evt_t * NH + j] - pcb[(size_t)evt_start * NH + j]) / evt_den;
        float pv = (lpe_eff >= 0) ? pew[lpe_eff * NH + j] : 0.f;
        sh_x[j] = tanhf(pv + avg + b_cmb[j]);
    }
    __syncthreads();

    // ---- x-half matvec — float4 over rho, 16 chunks x 24 k (384 thr) ----
    {
        const int q = tid % 24;        // rho-quad
        const int c = tid / 24;        // k-chunk: k in [24c, 24c+24)
        const float4* wp = (const float4*)(SLw + (size_t)(c * 24) * RS) + q;
        const float* xp = sh_x + c * 24;
        float4 acc = {0.f, 0.f, 0.f, 0.f};
        #pragma unroll 8
        for (int k = 0; k < 24; ++k) {
            float4 w = wp[(size_t)k * 24];
            float x = xp[k];
            acc.x += w.x * x; acc.y += w.y * x; acc.z += w.z * x; acc.w += w.w * x;
        }
        *(float4*)&sh_part[c * 96 + q * 4] = acc;
    }
    __syncthreads();

    // ---- merged gate-sum + gate-apply (tid<24) ----
    if (tid < JS) {
        float gv[4];
        #pragma unroll
        for (int g4 = 0; g4 < 4; ++g4) {
            const int rho = g4 * JS + tid;
            float a = bsum[g4 * NH + rh * JS + tid];
            #pragma unroll
            for (int c = 0; c < 16; ++c) a += sh_part[c * 96 + rho];
            #pragma unroll
            for (int c = 0; c < 12; ++c) a += sh_ph[c * 96 + rho];
            gv[g4] = a;
        }
        float c2 = sigmf(gv[1]) * creg + sigmf(gv[0]) * tanhf(gv[2]);
        float h2 = sigmf(gv[3]) * tanhf(c2);
        cst[rh * JS + tid] = c2;
        h_w[rh * JS + tid] = h2;
        sh_h2[tid] = h2;
    }
    __syncthreads();
    if (tid < NL) {
        const float* wr = W_lin + (size_t)tid * 1152 + rh * JS;
        float a = 0.f;
        #pragma unroll
        for (int k = 0; k < JS; ++k) a += wr[k] * sh_h2[k];
        hWbp_w[rh * 36 + tid] = a;
    }
}

// ---- k_finish: guaranteed completion past ROUNDS events (expected no-op) --
__global__ __launch_bounds__(384) void k_finish(
    const int* __restrict__ char_sizes,
    const int* __restrict__ label_is_sep, const int* __restrict__ label_pos_id,
    const float* __restrict__ W_lin, const float* __restrict__ b_lin,
    const float* __restrict__ b_cmb, float* __restrict__ ws,
    float* __restrict__ out) {

    const int s = blockIdx.x, tid = threadIdx.x;
    const int lane = tid & 63, wave = tid >> 6;
    float* stf = ws + OFF_STATE + (size_t)s * ST_STRIDE;
    int* ii = (int*)stf;                       // slot 0 (ROUNDS even)
    if (ii[IX_DONE]) return;

    const float* SL   = ws + OFF_SL;
    const float* pew  = ws + OFF_PEW;
    const float* bsum = ws + OFF_BS;
    const float* pcb  = ws + OFF_PC + (size_t)s * 1025 * NH;
    const float* eWb  = ws + OFF_ENCW + (size_t)s * NT * NL;
    float* outb = out + (size_t)s * NT * NL;

    __shared__ float sh_h[NH], sh_x[NH], sh_red[264], sh_hWb[40];
    __shared__ int sh_issep[NL], sh_posid[NL], sh_scan[8];

    sh_h[tid] = stf[SX_H + tid];               // slot-0 h
    float creg = stf[SX_C + tid];
    if (tid < NL) { sh_issep[tid] = label_is_sep[tid]; sh_posid[tid] = label_pos_id[tid]; }
    int t = ii[IX_T], wlen = ii[IX_WLEN], nw = ii[IX_NW], npos = ii[IX_NPOS],
        plast = ii[IX_PLAST], lpe_pend = ii[IX_LPEP], lpe_eff = ii[IX_LPEE];
    int size = char_sizes[s]; if (size > NT) size = NT;
    __syncthreads();

    for (int iter = 0; iter < 1100; ++iter) {
        if (tid < 264) {
            const int l = tid >> 3, p = tid & 7;
            const float* wr = W_lin + (size_t)l * 1152 + p * 48;
            const float* hp = sh_h + p * 48;
            float a = 0.f;
            #pragma unroll
            for (int k = 0; k < 48; ++k) a += wr[k] * hp[k];
            sh_red[tid] = a;
        }
        __syncthreads();
        if (tid < NL) {
            float q = b_lin[tid];
            #pragma unroll
            for (int p = 0; p < 8; ++p) q += sh_red[tid * 8 + p];
            sh_hWb[tid] = q;
        }
        __syncthreads();

        if (wave == 0) {
            int evt_t = -1, evt_start = 0; float evt_den = 1.f;
            for (; t < size; ++t) {
                float ot = (lane < NL) ? tanhf(eWb[(size_t)t * NL + lane] + sh_hWb[lane]) : -INFINITY;
                float bv = ot; int bi = lane;
                #pragma unroll
                for (int d = 32; d; d >>= 1) {
                    float ov = __shfl_xor(bv, d);
                    int   oi = __shfl_xor(bi, d);
                    if (ov > bv || (ov == bv && oi < bi)) { bv = ov; bi = oi; }
                }
                const int aid = bi;
                if (lane < NL) outb[(size_t)t * NL + lane] = ot;
                const int issep = sh_issep[aid];
                const int wl_prev = wlen;
                int nw_new;
                if (issep) { npos += 1; nw_new = nw + 1; }
                else       { nw_new = (nw < 1) ? 1 : nw; }
                const int do_l = issep && (nw_new >= 2);
                if (issep && npos >= 2) lpe_pend = plast;
                if (issep) plast = sh_posid[aid];
                wlen = issep ? 1 : wlen + 1;
                nw = nw_new;
                if (do_l) {
                    evt_t = t;
                    evt_start = (t - wl_prev < 0) ? 0 : (t - wl_prev);
                    evt_den = (float)((wl_prev < 1) ? 1 : wl_prev);
                    if (lpe_pend >= 0) { lpe_eff = lpe_pend; lpe_pend = -1; }
                    ++t;
                    break;
                }
            }
            if (lane == 0) {
                sh_scan[0] = evt_t; sh_scan[1] = evt_start;
                sh_scan[2] = __float_as_int(evt_den); sh_scan[3] = lpe_eff;
            }
        }
        __syncthreads();
        const int evt_t = sh_scan[0];
        if (evt_t < 0) break;
        const int evt_start = sh_scan[1];
        const float evt_den = __int_as_float(sh_scan[2]);
        const int lpe_e = sh_scan[3];

        {
            const int j = tid;
            float avg = (pcb[(size_t)evt_t * NH + j] - pcb[(size_t)evt_start * NH + j]) / evt_den;
            float pv = (lpe_e >= 0) ? pew[lpe_e * NH + j] : 0.f;
            sh_x[j] = tanhf(pv + avg + b_cmb[j]);
        }
        __syncthreads();

        // full matvec: thread j=tid, 4 gates; SL[sl][k][rho] k-major
        const int sl = tid / JS, jj = tid - sl * JS;
        const float* base = SL + (size_t)sl * (NE * RS);
        float gv[4];
        #pragma unroll
        for (int g4 = 0; g4 < 4; ++g4) {
            const int rho = g4 * JS + jj;
            const float* wp = base + rho;
            float a0 = 0.f, a1 = 0.f;
            for (int k = 0; k < NH; k += 2) {
                a0 += wp[(size_t)k * RS] * sh_x[k];
                a1 += wp[(size_t)(k + 1) * RS] * sh_x[k + 1];
            }
            for (int k = 0; k < NH; k += 2) {
                a0 += wp[(size_t)(NH + k) * RS] * sh_h[k];
                a1 += wp[(size_t)(NH + k + 1) * RS] * sh_h[k + 1];
            }
            gv[g4] = a0 + a1 + bsum[g4 * NH + tid];
        }
        float c2 = sigmf(gv[1]) * creg + sigmf(gv[0]) * tanhf(gv[2]);
        float h2 = sigmf(gv[3]) * tanhf(c2);
        creg = c2;
        __syncthreads();
        sh_h[tid] = h2;
        __syncthreads();
    }
}

// ---- parallel log-softmax -------------------------------------------------
__global__ void k_post(float* __restrict__ out) {
    int row = blockIdx.x * 4 + (threadIdx.x >> 6);
    int lane = threadIdx.x & 63;
    if (row >= NB * NT) return;
    float* p = out + (size_t)row * NL;
    float x = (lane < NL) ? p[lane] : -INFINITY;
    float m = x;
    #pragma unroll
    for (int d = 32; d; d >>= 1) m = fmaxf(m, __shfl_xor(m, d));
    float e = (lane < NL) ? expf(x - m) : 0.f;
    float su = e;
    #pragma unroll
    for (int d = 32; d; d >>= 1) su += __shfl_xor(su, d);
    if (lane < NL) p[lane] = (x - m) - logf(su);
}

extern "C" void kernel_launch(void* const* d_in, const int* in_sizes, int n_in,
                              void* d_out, int out_size, void* d_ws, size_t ws_size,
                              hipStream_t stream) {
    const float* enc          = (const float*)d_in[0];
    const int*   char_sizes   = (const int*)d_in[1];
    const int*   label_is_sep = (const int*)d_in[2];
    const int*   label_pos_id = (const int*)d_in[3];
    const float* posEmb       = (const float*)d_in[4];
    const float* W_ih         = (const float*)d_in[5];
    const float* W_hh         = (const float*)d_in[6];
    const float* b_ih         = (const float*)d_in[7];
    const float* b_hh         = (const float*)d_in[8];
    const float* W_lin        = (const float*)d_in[9];
    const float* b_lin        = (const float*)d_in[10];
    const float* W_cmb        = (const float*)d_in[11];
    const float* b_cmb        = (const float*)d_in[12];
    float* out = (float*)d_out;
    float* ws  = (float*)d_ws;

    hipLaunchKernelGGL(k_prep, dim3(1024), dim3(256), 0, stream,
                       W_ih, W_hh, W_cmb, posEmb, ws);
    hipLaunchKernelGGL(k_encw, dim3((NB * NT * NL + 255) / 256), dim3(256), 0, stream,
                       enc, W_lin, ws);
    hipLaunchKernelGGL(k_encCmb, dim3(1024), dim3(384), 0, stream, enc, W_cmb, ws);
    hipLaunchKernelGGL(k_prefix, dim3((NB * NH + 255) / 256), dim3(256), 0, stream, ws);
    hipLaunchKernelGGL(k_init, dim3(1), dim3(1024), 0, stream,
                       b_ih, b_hh, W_lin, b_lin, ws);
    hipLaunchKernelGGL(k_fill, dim3((NB * NT * NL + 255) / 256), dim3(256), 0, stream, out);

    for (int r = 0; r < ROUNDS; ++r) {
        hipLaunchKernelGGL(k_round, dim3(256), dim3(384), 0, stream,
                           char_sizes, label_is_sep, label_pos_id,
                           W_lin, b_lin, b_cmb, ws, out, r & 1);
    }
    hipLaunchKernelGGL(k_finish, dim3(NB), dim3(384), 0, stream,
                       char_sizes, label_is_sep, label_pos_id,
                       W_lin, b_lin, b_cmb, ws, out);

    hipLaunchKernelGGL(k_post, dim3((NB * NT + 3) / 4), dim3(256), 0, stream, out);
}